// Round 1
// baseline (1343.839 us; speedup 1.0000x reference)
//
#include <hip/hip_runtime.h>
#include <cstddef>

// ---------------------------------------------------------------------------
// GCN: out = relu(Â relu(Â relu(Â (x W0)) W1) W2),  Â = D^-1/2 (A+I) D^-1/2
// Strategy: aggregate-last per layer (GEMM -> edge scatter -> fused
// self-loop + ReLU finalize). Scatter: one wave per edge, lane = feature.
// ---------------------------------------------------------------------------

__global__ void deg_kernel(const int* __restrict__ dst, int E, int* __restrict__ cnt) {
    int i = blockIdx.x * blockDim.x + threadIdx.x;
    if (i < E) atomicAdd(&cnt[dst[i]], 1);
}

__global__ void dinv_kernel(const int* __restrict__ cnt, float* __restrict__ dinv, int N) {
    int i = blockIdx.x * blockDim.x + threadIdx.x;
    if (i < N) dinv[i] = rsqrtf((float)cnt[i] + 1.0f);  // +1 self-loop; deg>0 always
}

// A[N,K] @ W[K,M] -> out[N,M].  Block = 256 thr = 4 rows x 64 cols, W staged
// in LDS once per block (grid-stride over rows amortizes the W load).
template <int K, int M>
__global__ __launch_bounds__(256) void gemm_kernel(const float* __restrict__ A,
                                                   const float* __restrict__ W,
                                                   float* __restrict__ out, int N) {
    constexpr int ROWS = 4;
    __shared__ float Ws[K * M];
    __shared__ float As[ROWS][K];
    for (int i = threadIdx.x; i < K * M; i += 256) Ws[i] = W[i];
    const int col = threadIdx.x & 63;
    const int rl  = threadIdx.x >> 6;
    for (int row0 = blockIdx.x * ROWS; row0 < N; row0 += gridDim.x * ROWS) {
        __syncthreads();  // covers Ws load on iter 0, As reuse afterwards
        for (int i = threadIdx.x; i < ROWS * K; i += 256) {
            int r = i / K, k = i - r * K;
            int row = row0 + r;
            As[r][k] = (row < N) ? A[(size_t)row * K + k] : 0.0f;
        }
        __syncthreads();
        int row = row0 + rl;
        if (row < N && col < M) {
            float acc = 0.0f;
#pragma unroll
            for (int k = 0; k < K; ++k) acc = fmaf(As[rl][k], Ws[k * M + col], acc);
            out[(size_t)row * M + col] = acc;
        }
    }
}

// One wave per edge; lane i handles feature i. Coalesced 256B gather of
// t[src], wave-wide atomic add into acc[dst].
template <int D>
__global__ __launch_bounds__(256) void scatter_kernel(const float* __restrict__ t,
                                                      const int* __restrict__ src,
                                                      const int* __restrict__ dst,
                                                      const float* __restrict__ dinv,
                                                      float* __restrict__ acc, int E) {
    int e = blockIdx.x * 4 + (threadIdx.x >> 6);
    if (e >= E) return;
    int lane = threadIdx.x & 63;
    int s = src[e];
    int d = dst[e];
    float nrm = dinv[s] * dinv[d];
    if (D == 64 || lane < D) {
        atomicAdd(&acc[(size_t)d * D + lane], t[(size_t)s * D + lane] * nrm);
    }
}

// h[n][f] = relu(acc[n][f] + t[n][f] * dinv[n]^2)   (self-loop fused here)
template <int D>
__global__ void finalize_kernel(const float* __restrict__ acc, const float* __restrict__ t,
                                const float* __restrict__ dinv, float* __restrict__ out,
                                int N) {
    int idx = blockIdx.x * blockDim.x + threadIdx.x;
    if (idx < N * D) {
        int n = idx / D;
        float di = dinv[n];
        float v = acc[idx] + t[idx] * di * di;
        out[idx] = v > 0.0f ? v : 0.0f;
    }
}

extern "C" void kernel_launch(void* const* d_in, const int* in_sizes, int n_in,
                              void* d_out, int out_size, void* d_ws, size_t ws_size,
                              hipStream_t stream) {
    const float* x  = (const float*)d_in[0];
    const int*   ei = (const int*)d_in[1];   // [2, E] row-major, int32
    const float* W0 = (const float*)d_in[2]; // [128,64]
    const float* W1 = (const float*)d_in[3]; // [64,64]
    const float* W2 = (const float*)d_in[4]; // [64,40]
    float* out = (float*)d_out;

    const int N = in_sizes[0] / 128;
    const int E = in_sizes[1] / 2;
    const int* src = ei;
    const int* dst = ei + E;

    char* w = (char*)d_ws;
    size_t off = 0;
    auto alloc = [&](size_t bytes) {
        void* p = w + off;
        off += bytes;
        off = (off + 255) & ~(size_t)255;
        return p;
    };
    int*   cnt  = (int*)alloc((size_t)N * 4);
    float* dinv = (float*)alloc((size_t)N * 4);
    float* B1   = (float*)alloc((size_t)N * 64 * 4);
    float* B2   = (float*)alloc((size_t)N * 64 * 4);
    float* B3   = (float*)alloc((size_t)N * 64 * 4);

    // --- normalization ---
    hipMemsetAsync(cnt, 0, (size_t)N * 4, stream);
    deg_kernel<<<(E + 255) / 256, 256, 0, stream>>>(dst, E, cnt);
    dinv_kernel<<<(N + 255) / 256, 256, 0, stream>>>(cnt, dinv, N);

    // --- layer 0: x[N,128] @ W0 -> scatter(64) -> relu -> B2 ---
    gemm_kernel<128, 64><<<2048, 256, 0, stream>>>(x, W0, B2, N);
    hipMemsetAsync(B3, 0, (size_t)N * 64 * 4, stream);
    scatter_kernel<64><<<(E + 3) / 4, 256, 0, stream>>>(B2, src, dst, dinv, B3, E);
    finalize_kernel<64><<<(N * 64 + 255) / 256, 256, 0, stream>>>(B3, B2, dinv, B2, N);

    // --- layer 1: B2[N,64] @ W1 -> scatter(64) -> relu -> B1 ---
    gemm_kernel<64, 64><<<2048, 256, 0, stream>>>(B2, W1, B1, N);
    hipMemsetAsync(B3, 0, (size_t)N * 64 * 4, stream);
    scatter_kernel<64><<<(E + 3) / 4, 256, 0, stream>>>(B1, src, dst, dinv, B3, E);
    finalize_kernel<64><<<(N * 64 + 255) / 256, 256, 0, stream>>>(B3, B1, dinv, B1, N);

    // --- layer 2: B1[N,64] @ W2 -> scatter(40) -> relu -> out ---
    gemm_kernel<64, 40><<<2048, 256, 0, stream>>>(B1, W2, B2, N);
    hipMemsetAsync(B3, 0, (size_t)N * 40 * 4, stream);
    scatter_kernel<40><<<(E + 3) / 4, 256, 0, stream>>>(B2, src, dst, dinv, B3, E);
    finalize_kernel<40><<<(N * 40 + 255) / 256, 256, 0, stream>>>(B3, B2, dinv, out, N);
}

// Round 2
// 695.502 us; speedup vs baseline: 1.9322x; 1.9322x over previous
//
#include <hip/hip_runtime.h>
#include <cstddef>

// ---------------------------------------------------------------------------
// GCN: out = relu(Â relu(Â relu(Â (x W0)) W1) W2),  Â = D^-1/2 (A+I) D^-1/2
// R2 strategy: build dst-CSR once per call, then GATHER-side aggregation
// (no fp32 atomics). Per layer: GEMM -> agg(gather+selfloop+ReLU fused).
// ---------------------------------------------------------------------------

struct EdgeRec { int src; float norm; };  // 8B, one wave-uniform load per edge

__global__ void deg_kernel(const int* __restrict__ dst, int E, int* __restrict__ cnt) {
    int i = blockIdx.x * blockDim.x + threadIdx.x;
    if (i < E) atomicAdd(&cnt[dst[i]], 1);
}

__global__ void dinv_kernel(const int* __restrict__ cnt, float* __restrict__ dinv, int N) {
    int i = blockIdx.x * blockDim.x + threadIdx.x;
    if (i < N) dinv[i] = rsqrtf((float)cnt[i] + 1.0f);  // +1 self-loop; deg>0 always
}

// ---- exclusive scan of cnt[N] -> rowptr[N] (3-kernel, 4096 items/block) ----
constexpr int SCAN_ITEMS = 16;           // per thread
constexpr int SCAN_CHUNK = 256 * SCAN_ITEMS;  // 4096 per block

__global__ __launch_bounds__(256) void scan1_kernel(const int* __restrict__ cnt,
                                                    int* __restrict__ rowptr,
                                                    int* __restrict__ blockSums, int N) {
    __shared__ int sh[256];
    int tbase = blockIdx.x * SCAN_CHUNK + threadIdx.x * SCAN_ITEMS;
    int vals[SCAN_ITEMS];
    int tsum = 0;
#pragma unroll
    for (int j = 0; j < SCAN_ITEMS; ++j) {
        int idx = tbase + j;
        int v = (idx < N) ? cnt[idx] : 0;
        vals[j] = tsum;           // exclusive within thread
        tsum += v;
    }
    sh[threadIdx.x] = tsum;
    __syncthreads();
    // Hillis-Steele inclusive scan over 256 thread sums
    for (int off = 1; off < 256; off <<= 1) {
        int v = (threadIdx.x >= off) ? sh[threadIdx.x - off] : 0;
        __syncthreads();
        sh[threadIdx.x] += v;
        __syncthreads();
    }
    int texcl = sh[threadIdx.x] - tsum;   // exclusive across threads
    if (threadIdx.x == 255) blockSums[blockIdx.x] = sh[255];
#pragma unroll
    for (int j = 0; j < SCAN_ITEMS; ++j) {
        int idx = tbase + j;
        if (idx < N) rowptr[idx] = texcl + vals[j];
    }
}

__global__ void scan2_kernel(int* __restrict__ blockSums, int nb) {
    if (threadIdx.x == 0 && blockIdx.x == 0) {
        int run = 0;
        for (int i = 0; i < nb; ++i) { int v = blockSums[i]; blockSums[i] = run; run += v; }
    }
}

// add block offsets; also init cursor = rowptr and write rowptr[N] = E
__global__ __launch_bounds__(256) void scan3_kernel(int* __restrict__ rowptr,
                                                    int* __restrict__ cursor,
                                                    const int* __restrict__ blockSums,
                                                    int N, int E) {
    int idx = blockIdx.x * blockDim.x + threadIdx.x;
    if (idx < N) {
        int r = rowptr[idx] + blockSums[idx / SCAN_CHUNK];
        rowptr[idx] = r;
        cursor[idx] = r;
    }
    if (idx == 0) rowptr[N] = E;
}

__global__ void fill_kernel(const int* __restrict__ src, const int* __restrict__ dst,
                            const float* __restrict__ dinv, int* __restrict__ cursor,
                            EdgeRec* __restrict__ rec, int E) {
    int e = blockIdx.x * blockDim.x + threadIdx.x;
    if (e < E) {
        int s = src[e], d = dst[e];
        int slot = atomicAdd(&cursor[d], 1);
        EdgeRec r; r.src = s; r.norm = dinv[s] * dinv[d];
        rec[slot] = r;
    }
}

// A[N,K] @ W[K,M] -> out[N,M].  Block = 256 thr = 4 rows x 64 cols, W in LDS.
template <int K, int M>
__global__ __launch_bounds__(256) void gemm_kernel(const float* __restrict__ A,
                                                   const float* __restrict__ W,
                                                   float* __restrict__ out, int N) {
    constexpr int ROWS = 4;
    __shared__ float Ws[K * M];
    __shared__ float As[ROWS][K];
    for (int i = threadIdx.x; i < K * M; i += 256) Ws[i] = W[i];
    const int col = threadIdx.x & 63;
    const int rl  = threadIdx.x >> 6;
    for (int row0 = blockIdx.x * ROWS; row0 < N; row0 += gridDim.x * ROWS) {
        __syncthreads();  // covers Ws load on iter 0, As reuse afterwards
        for (int i = threadIdx.x; i < ROWS * K; i += 256) {
            int r = i / K, k = i - r * K;
            int row = row0 + r;
            As[r][k] = (row < N) ? A[(size_t)row * K + k] : 0.0f;
        }
        __syncthreads();
        int row = row0 + rl;
        if (row < N && col < M) {
            float acc = 0.0f;
#pragma unroll
            for (int k = 0; k < K; ++k) acc = fmaf(As[rl][k], Ws[k * M + col], acc);
            out[(size_t)row * M + col] = acc;
        }
    }
}

// Gather-side aggregation: one wave per node, lane = feature.
// out[n][f] = relu( sum_{e in CSR[n]} t[src_e][f]*norm_e + t[n][f]*dinv[n]^2 )
template <int D>
__global__ __launch_bounds__(256) void agg_kernel(const float* __restrict__ t,
                                                  const int* __restrict__ rowptr,
                                                  const EdgeRec* __restrict__ rec,
                                                  const float* __restrict__ dinv,
                                                  float* __restrict__ out, int N) {
    int n = blockIdx.x * 4 + (threadIdx.x >> 6);
    if (n >= N) return;
    int lane = threadIdx.x & 63;
    int beg = rowptr[n], end = rowptr[n + 1];
    if (D == 64 || lane < D) {
        float di = dinv[n];
        float acc = t[(size_t)n * D + lane] * di * di;   // self-loop
        int i = beg;
        for (; i + 1 < end; i += 2) {   // 2x unroll: both gathers in flight
            EdgeRec r0 = rec[i];
            EdgeRec r1 = rec[i + 1];
            float v0 = t[(size_t)r0.src * D + lane];
            float v1 = t[(size_t)r1.src * D + lane];
            acc = fmaf(v0, r0.norm, acc);
            acc = fmaf(v1, r1.norm, acc);
        }
        if (i < end) {
            EdgeRec r0 = rec[i];
            acc = fmaf(t[(size_t)r0.src * D + lane], r0.norm, acc);
        }
        out[(size_t)n * D + lane] = acc > 0.0f ? acc : 0.0f;
    }
}

extern "C" void kernel_launch(void* const* d_in, const int* in_sizes, int n_in,
                              void* d_out, int out_size, void* d_ws, size_t ws_size,
                              hipStream_t stream) {
    const float* x  = (const float*)d_in[0];
    const int*   ei = (const int*)d_in[1];   // [2, E] row-major, int32
    const float* W0 = (const float*)d_in[2]; // [128,64]
    const float* W1 = (const float*)d_in[3]; // [64,64]
    const float* W2 = (const float*)d_in[4]; // [64,40]
    float* out = (float*)d_out;

    const int N = in_sizes[0] / 128;
    const int E = in_sizes[1] / 2;
    const int* src = ei;
    const int* dst = ei + E;

    char* w = (char*)d_ws;
    size_t off = 0;
    auto alloc = [&](size_t bytes) {
        void* p = w + off;
        off += bytes;
        off = (off + 255) & ~(size_t)255;
        return p;
    };
    int*     cnt    = (int*)alloc((size_t)N * 4);
    float*   dinv   = (float*)alloc((size_t)N * 4);
    int*     rowptr = (int*)alloc((size_t)(N + 1) * 4);
    int*     cursor = (int*)alloc((size_t)N * 4);
    int*     bsums  = (int*)alloc(4096);
    EdgeRec* rec    = (EdgeRec*)alloc((size_t)E * 8);
    float*   B1     = (float*)alloc((size_t)N * 64 * 4);
    float*   B2     = (float*)alloc((size_t)N * 64 * 4);

    const int nScanBlocks = (N + SCAN_CHUNK - 1) / SCAN_CHUNK;

    // --- normalization + CSR build (once per call, reused by 3 layers) ---
    hipMemsetAsync(cnt, 0, (size_t)N * 4, stream);
    deg_kernel<<<(E + 255) / 256, 256, 0, stream>>>(dst, E, cnt);
    dinv_kernel<<<(N + 255) / 256, 256, 0, stream>>>(cnt, dinv, N);
    scan1_kernel<<<nScanBlocks, 256, 0, stream>>>(cnt, rowptr, bsums, N);
    scan2_kernel<<<1, 64, 0, stream>>>(bsums, nScanBlocks);
    scan3_kernel<<<(N + 255) / 256, 256, 0, stream>>>(rowptr, cursor, bsums, N, E);
    fill_kernel<<<(E + 255) / 256, 256, 0, stream>>>(src, dst, dinv, cursor, rec, E);

    // --- layer 0: x[N,128] @ W0 -> B1; agg -> B2 ---
    gemm_kernel<128, 64><<<2048, 256, 0, stream>>>(x, W0, B1, N);
    agg_kernel<64><<<(N + 3) / 4, 256, 0, stream>>>(B1, rowptr, rec, dinv, B2, N);

    // --- layer 1: B2 @ W1 -> B1; agg -> B2 ---
    gemm_kernel<64, 64><<<2048, 256, 0, stream>>>(B2, W1, B1, N);
    agg_kernel<64><<<(N + 3) / 4, 256, 0, stream>>>(B1, rowptr, rec, dinv, B2, N);

    // --- layer 2: B2 @ W2 -> B1; agg(40) -> out ---
    gemm_kernel<64, 40><<<2048, 256, 0, stream>>>(B2, W2, B1, N);
    agg_kernel<40><<<(N + 3) / 4, 256, 0, stream>>>(B1, rowptr, rec, dinv, out, N);
}

// Round 4
// 537.581 us; speedup vs baseline: 2.4998x; 1.2938x over previous
//
#include <hip/hip_runtime.h>
#include <cstddef>

// ---------------------------------------------------------------------------
// GCN: out = relu(Â relu(Â relu(Â (x W0)) W1) W2),  Â = D^-1/2 (A+I) D^-1/2
// R3 (resubmit after infra failure): register-tiled fp32 GEMM (transposed-A
// LDS staging, b128 reads) + half-wave-per-edge gather aggregation (2 rows
// per load instr, 4 gathers in flight). CSR built once; no fp32 atomics.
// ---------------------------------------------------------------------------

struct EdgeRec { int src; float norm; };  // 8B

__global__ void deg_kernel(const int* __restrict__ dst, int E, int* __restrict__ cnt) {
    int i = blockIdx.x * blockDim.x + threadIdx.x;
    if (i < E) atomicAdd(&cnt[dst[i]], 1);
}

__global__ void dinv_kernel(const int* __restrict__ cnt, float* __restrict__ dinv, int N) {
    int i = blockIdx.x * blockDim.x + threadIdx.x;
    if (i < N) dinv[i] = rsqrtf((float)cnt[i] + 1.0f);  // +1 self-loop; deg>0 always
}

// ---- exclusive scan of cnt[N] -> rowptr[N] (3-kernel, 4096 items/block) ----
constexpr int SCAN_ITEMS = 16;
constexpr int SCAN_CHUNK = 256 * SCAN_ITEMS;  // 4096

__global__ __launch_bounds__(256) void scan1_kernel(const int* __restrict__ cnt,
                                                    int* __restrict__ rowptr,
                                                    int* __restrict__ blockSums, int N) {
    __shared__ int sh[256];
    int tbase = blockIdx.x * SCAN_CHUNK + threadIdx.x * SCAN_ITEMS;
    int vals[SCAN_ITEMS];
    int tsum = 0;
#pragma unroll
    for (int j = 0; j < SCAN_ITEMS; ++j) {
        int idx = tbase + j;
        int v = (idx < N) ? cnt[idx] : 0;
        vals[j] = tsum;
        tsum += v;
    }
    sh[threadIdx.x] = tsum;
    __syncthreads();
    for (int off = 1; off < 256; off <<= 1) {
        int v = (threadIdx.x >= off) ? sh[threadIdx.x - off] : 0;
        __syncthreads();
        sh[threadIdx.x] += v;
        __syncthreads();
    }
    int texcl = sh[threadIdx.x] - tsum;
    if (threadIdx.x == 255) blockSums[blockIdx.x] = sh[255];
#pragma unroll
    for (int j = 0; j < SCAN_ITEMS; ++j) {
        int idx = tbase + j;
        if (idx < N) rowptr[idx] = texcl + vals[j];
    }
}

__global__ void scan2_kernel(int* __restrict__ blockSums, int nb) {
    if (threadIdx.x == 0 && blockIdx.x == 0) {
        int run = 0;
        for (int i = 0; i < nb; ++i) { int v = blockSums[i]; blockSums[i] = run; run += v; }
    }
}

__global__ __launch_bounds__(256) void scan3_kernel(int* __restrict__ rowptr,
                                                    int* __restrict__ cursor,
                                                    const int* __restrict__ blockSums,
                                                    int N, int E) {
    int idx = blockIdx.x * blockDim.x + threadIdx.x;
    if (idx < N) {
        int r = rowptr[idx] + blockSums[idx / SCAN_CHUNK];
        rowptr[idx] = r;
        cursor[idx] = r;
    }
    if (idx == 0) rowptr[N] = E;
}

__global__ void fill_kernel(const int* __restrict__ src, const int* __restrict__ dst,
                            const float* __restrict__ dinv, int* __restrict__ cursor,
                            EdgeRec* __restrict__ rec, int E) {
    int e = blockIdx.x * blockDim.x + threadIdx.x;
    if (e < E) {
        int s = src[e], d = dst[e];
        int slot = atomicAdd(&cursor[d], 1);
        EdgeRec r; r.src = s; r.norm = dinv[s] * dinv[d];
        rec[slot] = r;
    }
}

// ---------------------------------------------------------------------------
// Register-tiled GEMM: A[N,K] @ W[K,M] -> out[N,M].
// Block = 256 thr = 16x16 thread grid, 4x4 outputs/thread => 64 rows x 64 cols.
// W fully staged in LDS; A staged TRANSPOSED per 64-k chunk (stride 68 pad:
// a-reads b128 2-way/broadcast = conflict-free, b-reads b128 broadcast-free).
// ---------------------------------------------------------------------------
template <int K, int M>
__global__ __launch_bounds__(256) void gemm_kernel(const float* __restrict__ A,
                                                   const float* __restrict__ W,
                                                   float* __restrict__ out, int N) {
    constexpr int KC = 64;   // k-chunk
    constexpr int SA = 68;   // padded row stride of transposed A chunk
    __shared__ float Ws[K * M];
    __shared__ float As[KC * SA];   // As[k][row]
    for (int i = threadIdx.x; i < K * M; i += 256) Ws[i] = W[i];

    const int tr = threadIdx.x & 15;   // row group (0..15)
    const int tc = threadIdx.x >> 4;   // col group (0..15)
    const int r0 = tr * 4, c0 = tc * 4;
    const int row0 = blockIdx.x * 64;
    const bool colAct = (c0 < M);

    float acc[4][4] = {};

    for (int k0 = 0; k0 < K; k0 += KC) {
        __syncthreads();   // protect As from previous chunk's readers (and Ws on iter 0)
        {   // stage transpose: thread = (rr, kq); 16 rows x 16 k-quads per pass, 4 passes
            const int kq = threadIdx.x & 15;
            const int rr = threadIdx.x >> 4;
#pragma unroll
            for (int p = 0; p < 4; ++p) {
                int row = rr + p * 16;
                int grow = row0 + row;
                float4 v = make_float4(0.f, 0.f, 0.f, 0.f);
                if (grow < N)
                    v = *reinterpret_cast<const float4*>(&A[(size_t)grow * K + k0 + kq * 4]);
                As[(kq * 4 + 0) * SA + row] = v.x;
                As[(kq * 4 + 1) * SA + row] = v.y;
                As[(kq * 4 + 2) * SA + row] = v.z;
                As[(kq * 4 + 3) * SA + row] = v.w;
            }
        }
        __syncthreads();
        if (colAct) {
#pragma unroll 8
            for (int kk = 0; kk < KC; ++kk) {
                float4 a = *reinterpret_cast<const float4*>(&As[kk * SA + r0]);
                float4 b = *reinterpret_cast<const float4*>(&Ws[(k0 + kk) * M + c0]);
                acc[0][0] = fmaf(a.x, b.x, acc[0][0]); acc[0][1] = fmaf(a.x, b.y, acc[0][1]);
                acc[0][2] = fmaf(a.x, b.z, acc[0][2]); acc[0][3] = fmaf(a.x, b.w, acc[0][3]);
                acc[1][0] = fmaf(a.y, b.x, acc[1][0]); acc[1][1] = fmaf(a.y, b.y, acc[1][1]);
                acc[1][2] = fmaf(a.y, b.z, acc[1][2]); acc[1][3] = fmaf(a.y, b.w, acc[1][3]);
                acc[2][0] = fmaf(a.z, b.x, acc[2][0]); acc[2][1] = fmaf(a.z, b.y, acc[2][1]);
                acc[2][2] = fmaf(a.z, b.z, acc[2][2]); acc[2][3] = fmaf(a.z, b.w, acc[2][3]);
                acc[3][0] = fmaf(a.w, b.x, acc[3][0]); acc[3][1] = fmaf(a.w, b.y, acc[3][1]);
                acc[3][2] = fmaf(a.w, b.z, acc[3][2]); acc[3][3] = fmaf(a.w, b.w, acc[3][3]);
            }
        }
    }

    if (colAct) {
#pragma unroll
        for (int i = 0; i < 4; ++i) {
            int grow = row0 + r0 + i;
            if (grow < N) {
                float4 o = make_float4(acc[i][0], acc[i][1], acc[i][2], acc[i][3]);
                *reinterpret_cast<float4*>(&out[(size_t)grow * M + c0]) = o;
            }
        }
    }
}

// ---------------------------------------------------------------------------
// Gather aggregation: one wave per node; each 32-lane HALF processes a
// different edge (lane c = features 2c,2c+1 as float2) => 2 rows per load
// instruction, 2x unroll => 4 gathers in flight. Self-loop + ReLU fused.
// ---------------------------------------------------------------------------
template <int D>
__global__ __launch_bounds__(256) void agg_kernel(const float* __restrict__ t,
                                                  const int* __restrict__ rowptr,
                                                  const EdgeRec* __restrict__ rec,
                                                  const float* __restrict__ dinv,
                                                  float* __restrict__ out, int N) {
    int n = blockIdx.x * 4 + (threadIdx.x >> 6);
    if (n >= N) return;
    const int lane = threadIdx.x & 63;
    const int half = lane >> 5;
    const int f = (lane & 31) * 2;
    const bool act = (f < D);
    const int beg = rowptr[n], end = rowptr[n + 1];

    float ax = 0.f, ay = 0.f;
    if (half == 0 && act) {   // self-loop on half 0
        float di = dinv[n];
        float2 v = *reinterpret_cast<const float2*>(&t[(size_t)n * D + f]);
        ax = di * di * v.x;
        ay = di * di * v.y;
    }

    int i = beg + half;   // half 0: even offsets, half 1: odd offsets
    for (; i + 2 < end; i += 4) {
        EdgeRec r0 = rec[i];
        EdgeRec r1 = rec[i + 2];
        if (act) {
            float2 v0 = *reinterpret_cast<const float2*>(&t[(size_t)r0.src * D + f]);
            float2 v1 = *reinterpret_cast<const float2*>(&t[(size_t)r1.src * D + f]);
            ax = fmaf(v0.x, r0.norm, ax);
            ay = fmaf(v0.y, r0.norm, ay);
            ax = fmaf(v1.x, r1.norm, ax);
            ay = fmaf(v1.y, r1.norm, ay);
        }
    }
    for (; i < end; i += 2) {
        EdgeRec r = rec[i];
        if (act) {
            float2 v = *reinterpret_cast<const float2*>(&t[(size_t)r.src * D + f]);
            ax = fmaf(v.x, r.norm, ax);
            ay = fmaf(v.y, r.norm, ay);
        }
    }

    ax += __shfl_xor(ax, 32);
    ay += __shfl_xor(ay, 32);

    if (half == 0 && act) {
        float2 o;
        o.x = fmaxf(ax, 0.f);
        o.y = fmaxf(ay, 0.f);
        *reinterpret_cast<float2*>(&out[(size_t)n * D + f]) = o;
    }
}

extern "C" void kernel_launch(void* const* d_in, const int* in_sizes, int n_in,
                              void* d_out, int out_size, void* d_ws, size_t ws_size,
                              hipStream_t stream) {
    const float* x  = (const float*)d_in[0];
    const int*   ei = (const int*)d_in[1];   // [2, E] row-major, int32
    const float* W0 = (const float*)d_in[2]; // [128,64]
    const float* W1 = (const float*)d_in[3]; // [64,64]
    const float* W2 = (const float*)d_in[4]; // [64,40]
    float* out = (float*)d_out;

    const int N = in_sizes[0] / 128;
    const int E = in_sizes[1] / 2;
    const int* src = ei;
    const int* dst = ei + E;

    char* w = (char*)d_ws;
    size_t off = 0;
    auto alloc = [&](size_t bytes) {
        void* p = w + off;
        off += bytes;
        off = (off + 255) & ~(size_t)255;
        return p;
    };
    int*     cnt    = (int*)alloc((size_t)N * 4);
    float*   dinv   = (float*)alloc((size_t)N * 4);
    int*     rowptr = (int*)alloc((size_t)(N + 1) * 4);
    int*     cursor = (int*)alloc((size_t)N * 4);
    int*     bsums  = (int*)alloc(4096);
    EdgeRec* rec    = (EdgeRec*)alloc((size_t)E * 8);
    float*   B1     = (float*)alloc((size_t)N * 64 * 4);
    float*   B2     = (float*)alloc((size_t)N * 64 * 4);

    const int nScanBlocks = (N + SCAN_CHUNK - 1) / SCAN_CHUNK;

    // --- normalization + CSR build (reused by all 3 layers) ---
    hipMemsetAsync(cnt, 0, (size_t)N * 4, stream);
    deg_kernel<<<(E + 255) / 256, 256, 0, stream>>>(dst, E, cnt);
    dinv_kernel<<<(N + 255) / 256, 256, 0, stream>>>(cnt, dinv, N);
    scan1_kernel<<<nScanBlocks, 256, 0, stream>>>(cnt, rowptr, bsums, N);
    scan2_kernel<<<1, 64, 0, stream>>>(bsums, nScanBlocks);
    scan3_kernel<<<(N + 255) / 256, 256, 0, stream>>>(rowptr, cursor, bsums, N, E);
    fill_kernel<<<(E + 255) / 256, 256, 0, stream>>>(src, dst, dinv, cursor, rec, E);

    const int gemmGrid = (N + 63) / 64;

    // --- layer 0 ---
    gemm_kernel<128, 64><<<gemmGrid, 256, 0, stream>>>(x, W0, B1, N);
    agg_kernel<64><<<(N + 3) / 4, 256, 0, stream>>>(B1, rowptr, rec, dinv, B2, N);

    // --- layer 1 ---
    gemm_kernel<64, 64><<<gemmGrid, 256, 0, stream>>>(B2, W1, B1, N);
    agg_kernel<64><<<(N + 3) / 4, 256, 0, stream>>>(B1, rowptr, rec, dinv, B2, N);

    // --- layer 2 ---
    gemm_kernel<64, 40><<<gemmGrid, 256, 0, stream>>>(B2, W2, B1, N);
    agg_kernel<40><<<(N + 3) / 4, 256, 0, stream>>>(B1, rowptr, rec, dinv, out, N);
}